// Round 3
// baseline (824.644 us; speedup 1.0000x reference)
//
#include <hip/hip_runtime.h>
#include <stdint.h>

#define B_ 4
#define HC 256
#define WC 256
#define C_ 128
#define HF 512
#define WF 512
#define NPTS 8192
#define HIDDEN_ 256
#define NPIX (HC*WC)
#define GSTRIDE 132

// ---------------- copy coarse -> out ----------------
__global__ void pr_copy_kernel(const float4* __restrict__ src, float4* __restrict__ dst, int n4) {
    int i = blockIdx.x * blockDim.x + threadIdx.x;
    if (i < n4) dst[i] = src[i];
}

// ---------------- per-batch radix select of NPTS smallest |coarse|, ordered output ----------------
__global__ __launch_bounds__(1024) void pr_select_kernel(const float* __restrict__ coarse,
                                                         int* __restrict__ sel) {
    int b = blockIdx.x;
    const float* cb = coarse + (size_t)b * NPIX;
    int tid = threadIdx.x;
    int lane = tid & 63, wid = tid >> 6;
    int hc = wid >> 1;                      // histogram copy (8 copies)

    __shared__ unsigned hist[8][256];
    __shared__ unsigned s_prefix;
    __shared__ int s_remk;
    __shared__ unsigned wsum[16];
    __shared__ unsigned s_chosen, s_cless;
    __shared__ unsigned warp_eq[16], warp_take[16];
    __shared__ unsigned s_eqbase, s_outbase;

    if (tid == 0) { s_prefix = 0u; s_remk = NPTS; }

    for (int pass = 0; pass < 4; ++pass) {
        for (int i = tid; i < 2048; i += 1024) ((unsigned*)hist)[i] = 0u;
        __syncthreads();
        unsigned prefix = s_prefix;
        int remk = s_remk;
        int shift = 24 - 8 * pass;

        if (pass == 0) {
            // keys concentrate in a few exponent bins -> wave-aggregated atomics
            for (int i = 4 * tid; i < NPIX; i += 4096) {
                float4 v = *(const float4*)(cb + i);
                unsigned bins[4];
                bins[0] = (__float_as_uint(v.x) & 0x7fffffffu) >> 24;
                bins[1] = (__float_as_uint(v.y) & 0x7fffffffu) >> 24;
                bins[2] = (__float_as_uint(v.z) & 0x7fffffffu) >> 24;
                bins[3] = (__float_as_uint(v.w) & 0x7fffffffu) >> 24;
#pragma unroll
                for (int e = 0; e < 4; ++e) {
                    unsigned bin = bins[e];
                    unsigned long long am = ~0ull;
                    while (am) {
                        int leader = __ffsll((unsigned long long)am) - 1;
                        unsigned lbin = __shfl(bin, leader, 64);
                        unsigned long long match = __ballot(bin == lbin);
                        if (lane == leader) atomicAdd(&hist[hc][lbin], (unsigned)__popcll(match));
                        am &= ~match;
                    }
                }
            }
        } else {
            for (int i = 4 * tid; i < NPIX; i += 4096) {
                float4 v = *(const float4*)(cb + i);
                unsigned k0 = __float_as_uint(v.x) & 0x7fffffffu;
                unsigned k1 = __float_as_uint(v.y) & 0x7fffffffu;
                unsigned k2 = __float_as_uint(v.z) & 0x7fffffffu;
                unsigned k3 = __float_as_uint(v.w) & 0x7fffffffu;
                if ((k0 >> (shift + 8)) == prefix) atomicAdd(&hist[hc][(k0 >> shift) & 0xffu], 1u);
                if ((k1 >> (shift + 8)) == prefix) atomicAdd(&hist[hc][(k1 >> shift) & 0xffu], 1u);
                if ((k2 >> (shift + 8)) == prefix) atomicAdd(&hist[hc][(k2 >> shift) & 0xffu], 1u);
                if ((k3 >> (shift + 8)) == prefix) atomicAdd(&hist[hc][(k3 >> shift) & 0xffu], 1u);
            }
        }
        __syncthreads();

        // parallel choose: reduce 8 copies, inclusive scan over 256 bins (threads 0..255)
        unsigned h = 0, incl = 0;
        if (tid < 256) {
            h = hist[0][tid] + hist[1][tid] + hist[2][tid] + hist[3][tid]
              + hist[4][tid] + hist[5][tid] + hist[6][tid] + hist[7][tid];
            incl = h;
#pragma unroll
            for (int d = 1; d < 64; d <<= 1) {
                unsigned y = __shfl_up(incl, d, 64);
                if (lane >= d) incl += y;
            }
            if (lane == 63) wsum[wid] = incl;
        }
        __syncthreads();
        if (tid < 256) {
            unsigned base = 0;
            for (int w = 0; w < wid; ++w) base += wsum[w];
            unsigned inc = base + incl;
            unsigned exc = inc - h;
            if ((unsigned)remk > exc && (unsigned)remk <= inc) { s_chosen = (unsigned)tid; s_cless = exc; }
        }
        __syncthreads();
        if (tid == 0) { s_prefix = (s_prefix << 8) | s_chosen; s_remk = remk - (int)s_cless; }
        __syncthreads();
    }

    unsigned T = s_prefix;                 // key value of the NPTS-th smallest
    unsigned need_eq = (unsigned)s_remk;   // # of ==T ties to take, smallest index first
    if (tid == 0) { s_eqbase = 0u; s_outbase = 0u; }
    __syncthreads();

    unsigned long long ltmask = (1ull << lane) - 1ull;
    for (int base = 0; base < NPIX; base += 4096) {
        int i0 = base + 4 * tid;
        float4 v = *(const float4*)(cb + i0);
        unsigned k[4];
        k[0] = __float_as_uint(v.x) & 0x7fffffffu;
        k[1] = __float_as_uint(v.y) & 0x7fffffffu;
        k[2] = __float_as_uint(v.z) & 0x7fffffffu;
        k[3] = __float_as_uint(v.w) & 0x7fffffffu;
        bool lt[4], eq[4];
        unsigned long long me[4];
        unsigned weq = 0;
#pragma unroll
        for (int e = 0; e < 4; ++e) {
            lt[e] = k[e] < T;
            eq[e] = k[e] == T;
            me[e] = __ballot(eq[e]);
            weq += (unsigned)__popcll(me[e]);
        }
        if (lane == 0) warp_eq[wid] = weq;
        __syncthreads();

        unsigned eqwb = 0, eqtot = 0;
        for (int w = 0; w < 16; ++w) { unsigned hh = warp_eq[w]; if (w < wid) eqwb += hh; eqtot += hh; }
        unsigned lt_lanes_eq = 0;
#pragma unroll
        for (int e = 0; e < 4; ++e) lt_lanes_eq += (unsigned)__popcll(me[e] & ltmask);
        unsigned ebase = s_eqbase + eqwb + lt_lanes_eq;

        bool take[4];
        unsigned long long mt[4];
        unsigned self_eq = 0;
#pragma unroll
        for (int e = 0; e < 4; ++e) {
            unsigned eqrank = ebase + self_eq;
            take[e] = lt[e] || (eq[e] && eqrank < need_eq);
            self_eq += eq[e] ? 1u : 0u;
        }
        unsigned wtk = 0;
#pragma unroll
        for (int e = 0; e < 4; ++e) {
            mt[e] = __ballot(take[e]);
            wtk += (unsigned)__popcll(mt[e]);
        }
        if (lane == 0) warp_take[wid] = wtk;
        __syncthreads();

        unsigned twb = 0, ttot = 0;
        for (int w = 0; w < 16; ++w) { unsigned hh = warp_take[w]; if (w < wid) twb += hh; ttot += hh; }
        unsigned lt_lanes_tk = 0;
#pragma unroll
        for (int e = 0; e < 4; ++e) lt_lanes_tk += (unsigned)__popcll(mt[e] & ltmask);
        unsigned tbase = s_outbase + twb + lt_lanes_tk;
        unsigned self_tk = 0;
#pragma unroll
        for (int e = 0; e < 4; ++e) {
            if (take[e]) sel[b * NPTS + (int)(tbase + self_tk)] = i0 + e;
            self_tk += take[e] ? 1u : 0u;
        }
        __syncthreads();
        if (tid == 0) { s_eqbase += eqtot; s_outbase += ttot; }
    }
}

// ---------------- pure gather: max outstanding scattered loads ----------------
__global__ __launch_bounds__(256) void pr_gather_kernel(
    const float* __restrict__ coarse, const float* __restrict__ fine,
    const int* __restrict__ sel, float* __restrict__ feats) {
    int tid = threadIdx.x;
    int b = blockIdx.x >> 12;                 // 4096 blocks per batch (2 points each)
    int pbase = (blockIdx.x & 4095) * 2;
    __shared__ int sidx[2];
    if (tid < 2) sidx[tid] = sel[b * NPTS + pbase + tid];
    __syncthreads();
    int c = tid & 127, ph = tid >> 7;
    int id = sidx[ph];
    int ix = id & (WC - 1), iy = id >> 8;
    const float* a = fine + (size_t)(b * C_ + c) * (HF * WF) + (size_t)(2 * iy) * WF + 2 * ix;
    float2 r0 = *(const float2*)a;
    float2 r1 = *(const float2*)(a + WF);
    size_t o = (size_t)(b * NPTS + pbase + ph) * GSTRIDE;
    feats[o + c] = 0.25f * ((r0.x + r0.y) + (r1.x + r1.y));
    if (c == 0) feats[o + 128] = coarse[(size_t)b * NPIX + id];
}

// ---------------- MLP: j-blocked 4-wide, no LDS staging ----------------
__global__ __launch_bounds__(256) void pr_mlp_kernel(
    const float* __restrict__ feats, const float* __restrict__ W1,
    const float* __restrict__ b1, const float* __restrict__ W2,
    const float* __restrict__ b2, const int* __restrict__ sel,
    float* __restrict__ out) {
    __shared__ int sidx[32];
    int tid = threadIdx.x;
    int b = blockIdx.x >> 8;                  // 256 blocks per batch (32 points each)
    int pbase = (blockIdx.x & 255) * 32;
    if (tid < 32) sidx[tid] = sel[b * NPTS + pbase + tid];
    __syncthreads();

    int lane = tid & 63, wv = tid >> 6;       // lane = j-group (4 hidden units), wave owns 8 points
    float4 b14 = *(const float4*)&b1[4 * lane];
    float acc[8][4];
#pragma unroll
    for (int i = 0; i < 8; ++i) {
        acc[i][0] = b14.x; acc[i][1] = b14.y; acc[i][2] = b14.z; acc[i][3] = b14.w;
    }

    const float* frow = feats + (size_t)(b * NPTS + pbase + wv * 8) * GSTRIDE;
    const float4* f4p = (const float4*)frow;  // point i at float4 offset i*33

    for (int f4 = 0; f4 < 32; ++f4) {
        float4 w0 = *(const float4*)&W1[(4 * f4 + 0) * HIDDEN_ + 4 * lane];
        float4 w1v = *(const float4*)&W1[(4 * f4 + 1) * HIDDEN_ + 4 * lane];
        float4 w2v = *(const float4*)&W1[(4 * f4 + 2) * HIDDEN_ + 4 * lane];
        float4 w3v = *(const float4*)&W1[(4 * f4 + 3) * HIDDEN_ + 4 * lane];
#pragma unroll
        for (int i = 0; i < 8; ++i) {
            float4 fv = f4p[i * 33 + f4];     // uniform across lanes -> single-line broadcast
            acc[i][0] = fmaf(fv.x, w0.x, acc[i][0]);
            acc[i][1] = fmaf(fv.x, w0.y, acc[i][1]);
            acc[i][2] = fmaf(fv.x, w0.z, acc[i][2]);
            acc[i][3] = fmaf(fv.x, w0.w, acc[i][3]);
            acc[i][0] = fmaf(fv.y, w1v.x, acc[i][0]);
            acc[i][1] = fmaf(fv.y, w1v.y, acc[i][1]);
            acc[i][2] = fmaf(fv.y, w1v.z, acc[i][2]);
            acc[i][3] = fmaf(fv.y, w1v.w, acc[i][3]);
            acc[i][0] = fmaf(fv.z, w2v.x, acc[i][0]);
            acc[i][1] = fmaf(fv.z, w2v.y, acc[i][1]);
            acc[i][2] = fmaf(fv.z, w2v.z, acc[i][2]);
            acc[i][3] = fmaf(fv.z, w2v.w, acc[i][3]);
            acc[i][0] = fmaf(fv.w, w3v.x, acc[i][0]);
            acc[i][1] = fmaf(fv.w, w3v.y, acc[i][1]);
            acc[i][2] = fmaf(fv.w, w3v.z, acc[i][2]);
            acc[i][3] = fmaf(fv.w, w3v.w, acc[i][3]);
        }
    }
    {   // feature 128 (coarse logit)
        float4 wl = *(const float4*)&W1[128 * HIDDEN_ + 4 * lane];
#pragma unroll
        for (int i = 0; i < 8; ++i) {
            float fc = frow[i * GSTRIDE + 128];
            acc[i][0] = fmaf(fc, wl.x, acc[i][0]);
            acc[i][1] = fmaf(fc, wl.y, acc[i][1]);
            acc[i][2] = fmaf(fc, wl.z, acc[i][2]);
            acc[i][3] = fmaf(fc, wl.w, acc[i][3]);
        }
    }

    float4 w2f = *(const float4*)&W2[4 * lane];
    float bb = b2[0];
#pragma unroll
    for (int i = 0; i < 8; ++i) {
        float v = fmaxf(acc[i][0], 0.0f) * w2f.x
                + fmaxf(acc[i][1], 0.0f) * w2f.y
                + fmaxf(acc[i][2], 0.0f) * w2f.z
                + fmaxf(acc[i][3], 0.0f) * w2f.w;
        v += __shfl_down(v, 32, 64);
        v += __shfl_down(v, 16, 64);
        v += __shfl_down(v, 8, 64);
        v += __shfl_down(v, 4, 64);
        v += __shfl_down(v, 2, 64);
        v += __shfl_down(v, 1, 64);
        if (lane == 0) {
            int id = sidx[wv * 8 + i];
            out[(size_t)b * NPIX + id] = v + bb;
        }
    }
}

extern "C" void kernel_launch(void* const* d_in, const int* in_sizes, int n_in,
                              void* d_out, int out_size, void* d_ws, size_t ws_size,
                              hipStream_t stream) {
    const float* coarse = (const float*)d_in[0];
    const float* fine   = (const float*)d_in[1];
    const float* W1     = (const float*)d_in[2];
    const float* b1     = (const float*)d_in[3];
    const float* W2     = (const float*)d_in[4];
    const float* b2     = (const float*)d_in[5];
    float* out = (float*)d_out;
    int* sel = (int*)d_ws;                              // B_*NPTS ints = 128 KB
    float* feats = (float*)((char*)d_ws + (1 << 20));   // B_*NPTS*132 floats ~= 17.3 MB

    int n4 = B_ * NPIX / 4;
    pr_copy_kernel<<<(n4 + 255) / 256, 256, 0, stream>>>((const float4*)coarse, (float4*)out, n4);
    pr_select_kernel<<<B_, 1024, 0, stream>>>(coarse, sel);
    pr_gather_kernel<<<B_ * (NPTS / 2), 256, 0, stream>>>(coarse, fine, sel, feats);
    pr_mlp_kernel<<<B_ * (NPTS / 32), 256, 0, stream>>>(feats, W1, b1, W2, b2, sel, out);
}